// Round 3
// baseline (703.086 us; speedup 1.0000x reference)
//
#include <hip/hip_runtime.h>
#include <hip/hip_cooperative_groups.h>

namespace cg = cooperative_groups;

// ConvNet_STDP — single cooperative kernel, device-side time loop, exact
// dynamic early-exit + closed-form dead tail.
//
// Verified facts (rounds 1-2, absmax 0.0):
//  * STDP provably inert -> weight outputs are clip(w_init, 0, 1).
//  * Once m2 is all-zero at a step start, nothing downstream changes ->
//    break the time loop; LI recurrence computed in closed form.
//  * Round-2 diagnosis: 94% stall at 14.7% occupancy (320 blocks = 1.25
//    waves/SIMD). This round: 2048 blocks (8 waves/SIMD), 5 syncs/step,
//    conv2 via per-batch LDS staging + 4-lane ci-split.

#define T_STEPS 30
#define BATCH   32
#define H_IN    240
#define W_IN    160
#define C1      4
#define H1      236
#define W1O     156
#define H3      39
#define W3      25
#define C2      20
#define H2      24
#define W2O     10
#define H6      12
#define W6      5
#define C3      10
#define H8      8

#define N_V1   (BATCH*C1*H1*W1O)   // 4,712,448
#define N_V2   (BATCH*C2*H2*W2O)   // 153,600
#define N_V2PB (C2*H2*W2O)         // 4,800 per batch
#define N_V3   (BATCH*C3*H8)       // 2,560
#define N_Z3   (BATCH*C1*H3*W3)    // 124,800
#define Z3PB   (C1*H3*W3)          // 3,900 (= 975 dwords)
#define N_FEAT (BATCH*C3)          // 320

#define NTHR 256

__global__ __launch_bounds__(NTHR, 8) void snn_all(
    const float* __restrict__ x,     const float* __restrict__ w1,
    const float* __restrict__ w2,    const float* __restrict__ w3,
    const float* __restrict__ fc1_w, const float* __restrict__ fc1_b,
    const float* __restrict__ out_w, const float* __restrict__ out_b,
    float* __restrict__ out,
    float* v1, float* v2, float* v3,
    unsigned char* m1, unsigned char* m2, unsigned char* m3,
    unsigned char* z2, unsigned char* z3, unsigned char* z5,
    unsigned char* z8, int* alive2)
{
  cg::grid_group grid = cg::this_grid();
  const int tid = threadIdx.x;
  const int gid = blockIdx.x*NTHR + tid;
  const int gsz = gridDim.x*NTHR;

  __shared__ float s_w1[C1*25];
  __shared__ unsigned int s_z3w[Z3PB/4];   // per-batch z3 staging (3900 B)
  __shared__ float s_feat[N_FEAT];
  __shared__ float s_h[64];
  __shared__ float s_li[10], s_lv[10];
  __shared__ float s_tail[T_STEPS*10];
  __shared__ int   s_alive;

  // ---- init: weight-clip outputs (STDP inert), alive counter, LI state
  float* out_w1 = out + T_STEPS*N_FEAT;
  float* out_w2 = out_w1 + C1*25;
  for (int i = gid; i < C1*25;     i += gsz) out_w1[i] = fminf(fmaxf(w1[i], 0.f), 1.f);
  for (int i = gid; i < C2*C1*256; i += gsz) out_w2[i] = fminf(fmaxf(w2[i], 0.f), 1.f);
  if (gid == 0) *alive2 = N_V2;
  if (blockIdx.x == 0 && tid < 10) { s_li[tid] = 0.f; s_lv[tid] = 0.f; }
  for (int i = tid; i < C1*25; i += NTHR) s_w1[i] = w1[i];
  __syncthreads();

  int t = 0;
  for (; t < T_STEPS; ++t) {
    if (t > 0) {
      // alive2 finalized in S3 of step t-1 (>=2 grid syncs ago).
      if (tid == 0)
        s_alive = __hip_atomic_load(alive2, __ATOMIC_RELAXED, __HIP_MEMORY_SCOPE_AGENT);
      __syncthreads();
      if (s_alive == 0) break;   // uniform across grid
      __syncthreads();           // protect s_alive before next-step rewrite
    }
    const float* xt = x + (size_t)t*BATCH*H_IN*W_IN;

    // ---- S1: conv1 (1->4, 5x5) + IAF(10) + lateral-inhibition mask
    for (int idx = gid; idx < N_V1; idx += gsz) {
      int xw = idx % W1O; int tt = idx / W1O;
      int y  = tt % H1;   tt /= H1;
      int c  = tt % C1;   int b = tt / C1;
      const float* xp = xt + (size_t)(b*H_IN + y)*W_IN + xw;
      const float* wp = s_w1 + c*25;
      float s = 0.f;
      #pragma unroll
      for (int i = 0; i < 5; ++i)
        #pragma unroll
        for (int j = 0; j < 5; ++j) s = fmaf(xp[i*W_IN + j], wp[i*5 + j], s);
      float v = (t == 0 ? 0.f : v1[idx]) + s;
      bool  z = (v >= 10.0f);
      v1[idx] = z ? 0.f : v;                       // reset is mask-independent
      unsigned char m = (t == 0) ? 1 : m1[idx];
      z2[idx] = (z && m) ? 1 : 0;
      m1[idx] = (m && !z) ? 1 : 0;
    }
    grid.sync();

    // ---- S2: maxpool 7x7 stride 6 over binary spikes = OR
    for (int idx = gid; idx < N_Z3; idx += gsz) {
      int px = idx % W3; int tt = idx / W3;
      int py = tt % H3;  tt /= H3;
      int c  = tt % C1;  int b = tt / C1;
      const unsigned char* p = z2 + ((size_t)(b*C1 + c)*H1 + py*6)*W1O + px*6;
      unsigned char r = 0;
      #pragma unroll
      for (int i = 0; i < 7; ++i)
        #pragma unroll
        for (int j = 0; j < 7; ++j) r |= p[i*W1O + j];
      z3[idx] = r;
    }
    grid.sync();

    // ---- S3: conv2 (4->20, 16x16) + IAF(60) + mask. Per-batch LDS staging,
    //          4-lane input-channel split + shuffle reduce.
    {
      const int b   = blockIdx.x & 31;      // gridDim.x is a multiple of 32
      const int wb  = blockIdx.x >> 5;
      const int bpb = gridDim.x >> 5;       // blocks per batch
      const unsigned int* zsrc = (const unsigned int*)(z3 + (size_t)b*Z3PB);
      for (int i = tid; i < Z3PB/4; i += NTHR) s_z3w[i] = zsrc[i];
      __syncthreads();
      const unsigned char* sz = (const unsigned char*)s_z3w;
      int nf = 0;
      for (int it = wb*NTHR + tid; it < N_V2PB*4; it += bpb*NTHR) {
        int o = it >> 2, ci = it & 3;       // lanes 4k..4k+3 share o
        int c  = o / (H2*W2O);
        int r  = o - c*(H2*W2O);
        int oy = r / W2O, ox = r - (r/W2O)*W2O;
        const float* wp2 = w2 + ((size_t)c*C1 + ci)*256;
        const unsigned char* zb = sz + (ci*H3 + oy)*W3 + ox;
        float s = 0.f;
        #pragma unroll
        for (int i = 0; i < 16; ++i) {
          const unsigned char* ip = zb + i*W3;
          const float* wp = wp2 + i*16;
          #pragma unroll
          for (int j = 0; j < 16; ++j) s = fmaf((float)ip[j], wp[j], s);
        }
        s += __shfl_xor(s, 1, 64);
        s += __shfl_xor(s, 2, 64);
        if (ci == 0) {
          int gidx = b*N_V2PB + o;
          float v = (t == 0 ? 0.f : v2[gidx]) + s;
          bool  z = (v >= 60.0f);
          v2[gidx] = z ? 0.f : v;
          unsigned char m  = (t == 0) ? 1 : m2[gidx];
          unsigned char sp = (z && m) ? 1 : 0;
          z5[gidx] = sp;
          m2[gidx] = (m && !z) ? 1 : 0;
          nf += sp;
        }
      }
      #pragma unroll
      for (int o2 = 1; o2 < 64; o2 <<= 1) nf += __shfl_xor(nf, o2, 64);
      if ((tid & 63) == 0 && nf) atomicSub(alive2, nf);
    }
    grid.sync();

    // ---- S4: conv3 (20->10, 5x5) + IAF(2) + mask, pool2 folded into reads.
    //          One block per batch, 4-lane ci-group split.
    if (blockIdx.x < BATCH) {
      const int b = blockIdx.x;
      for (int it = tid; it < C3*H8*4; it += NTHR) {
        int o = it >> 2, g = it & 3;        // g: 5-channel group
        int c3 = o >> 3, oy = o & 7;
        float s = 0.f;
        for (int ci = g*5; ci < g*5 + 5; ++ci) {
          const unsigned char* zp = z5 + (size_t)(b*C2 + ci)*H2*W2O;
          const float* wp = w3 + ((size_t)c3*C2 + ci)*25;
          #pragma unroll
          for (int i = 0; i < 5; ++i) {
            const unsigned char* r0 = zp + (2*(oy + i))*W2O;
            const unsigned char* r1 = r0 + W2O;
            #pragma unroll
            for (int j = 0; j < 5; ++j) {
              unsigned char zv = r0[2*j] | r0[2*j+1] | r1[2*j] | r1[2*j+1];
              s = fmaf((float)zv, wp[i*5 + j], s);   // z6 = 2x2 OR of z5
            }
          }
        }
        s += __shfl_xor(s, 1, 64);
        s += __shfl_xor(s, 2, 64);
        if (g == 0) {
          int gidx = b*(C3*H8) + o;
          float v = (t == 0 ? 0.f : v3[gidx]) + s;
          bool  z = (v >= 2.0f);
          v3[gidx] = z ? 0.f : v;
          unsigned char m = (t == 0) ? 1 : m3[gidx];
          z8[gidx] = (z && m) ? 1 : 0;
          m3[gidx] = (m && !z) ? 1 : 0;
        }
      }
    }
    grid.sync();

    // ---- S5: feat -> fc1 -> relu -> LI cell -> volts[t]   (block 0)
    if (blockIdx.x == 0) {
      for (int i = tid; i < N_FEAT; i += NTHR) {     // z9: OR over 8 spatial
        const unsigned char* p = z8 + i*H8;
        unsigned char r = 0;
        #pragma unroll
        for (int k = 0; k < H8; ++k) r |= p[k];
        s_feat[i] = (float)r;
      }
      __syncthreads();
      {
        int o = tid >> 2, q = tid & 3;               // 4 lanes per fc1 output
        if (o < 50) {
          const float* wr = fc1_w + (size_t)o*N_FEAT + q*80;
          const float* fr = s_feat + q*80;
          float s = 0.f;
          for (int j = 0; j < 80; ++j) s = fmaf(fr[j], wr[j], s);
          s += __shfl_xor(s, 1, 64);
          s += __shfl_xor(s, 2, 64);
          if (q == 0) s_h[o] = fmaxf(s + fc1_b[o], 0.f);
        }
      }
      __syncthreads();
      if (tid < 10) {
        float idec = s_li[tid]*0.8f;                 // 1 - dt*tau_syn_inv
        float vnew = s_lv[tid] + 0.1f*(idec - s_lv[tid]);
        float acc = idec + out_b[tid];
        for (int k = 0; k < 50; ++k) acc = fmaf(s_h[k], out_w[tid*50 + k], acc);
        s_li[tid] = acc;
        s_lv[tid] = vnew;
      }
      __syncthreads();
      float* vt = out + (size_t)t*N_FEAT;
      for (int i = tid; i < N_FEAT; i += NTHR) vt[i] = s_lv[i % 10];
    }
    grid.sync();
  }

  // ---- closed-form dead tail: h = relu(fc1_b) constant, li/lv scalar decay
  if (t < T_STEPS && blockIdx.x == 0) {
    if (tid < 50) s_h[tid] = fmaxf(fc1_b[tid], 0.f);
    __syncthreads();
    if (tid < 10) {
      float c = out_b[tid];
      for (int k = 0; k < 50; ++k) c = fmaf(s_h[k], out_w[tid*50 + k], c);
      float li = s_li[tid], lv = s_lv[tid];
      for (int tt = t; tt < T_STEPS; ++tt) {
        float idec = li*0.8f;
        lv = lv + 0.1f*(idec - lv);
        li = idec + c;
        s_tail[(tt - t)*10 + tid] = lv;
      }
    }
    __syncthreads();
    int nrem = (T_STEPS - t)*N_FEAT;
    float* vt = out + (size_t)t*N_FEAT;
    for (int i = tid; i < nrem; i += NTHR)
      vt[i] = s_tail[(i/N_FEAT)*10 + (i % 10)];
  }
}

extern "C" void kernel_launch(void* const* d_in, const int* in_sizes, int n_in,
                              void* d_out, int out_size, void* d_ws, size_t ws_size,
                              hipStream_t stream) {
  const float* x      = (const float*)d_in[0];
  const float* w1     = (const float*)d_in[1];
  const float* w2     = (const float*)d_in[2];
  const float* w3     = (const float*)d_in[3];
  const float* fc1_w  = (const float*)d_in[4];
  const float* fc1_b  = (const float*)d_in[5];
  const float* out_w  = (const float*)d_in[6];
  const float* out_b  = (const float*)d_in[7];
  float* out = (float*)d_out;   // [volts 30*320 | w1 100 | w2 20480]

  char* p = (char*)d_ws;
  float* v1 = (float*)p;            p += (size_t)N_V1*4;
  float* v2 = (float*)p;            p += (size_t)N_V2*4;
  float* v3 = (float*)p;            p += (size_t)N_V3*4;
  int* alive2 = (int*)p;            p += 4;
  unsigned char* m1 = (unsigned char*)p;  p += N_V1;
  unsigned char* m2 = (unsigned char*)p;  p += N_V2;
  unsigned char* m3 = (unsigned char*)p;  p += N_V3;
  unsigned char* z2 = (unsigned char*)p;  p += N_V1;
  unsigned char* z3 = (unsigned char*)p;  p += N_Z3;
  unsigned char* z5 = (unsigned char*)p;  p += N_V2;
  unsigned char* z8 = (unsigned char*)p;  p += N_V3;

  // Grid: fill the machine, clamped to guaranteed cooperative co-residency.
  int bpc = 0, cus = 256;
  if (hipOccupancyMaxActiveBlocksPerMultiprocessor(&bpc, snn_all, NTHR, 0) != hipSuccess || bpc < 1)
    bpc = 1;
  (void)hipDeviceGetAttribute(&cus, hipDeviceAttributeMultiprocessorCount, 0);
  int nblk = bpc * cus;
  if (nblk > 2048) nblk = 2048;
  nblk -= nblk % 32;                // S3 batch mapping needs a multiple of 32
  if (nblk < 32) nblk = 32;

  void* args[] = {
    (void*)&x, (void*)&w1, (void*)&w2, (void*)&w3,
    (void*)&fc1_w, (void*)&fc1_b, (void*)&out_w, (void*)&out_b,
    (void*)&out,
    (void*)&v1, (void*)&v2, (void*)&v3,
    (void*)&m1, (void*)&m2, (void*)&m3,
    (void*)&z2, (void*)&z3, (void*)&z5, (void*)&z8,
    (void*)&alive2
  };
  hipLaunchCooperativeKernel(reinterpret_cast<void*>(snn_all),
                             dim3(nblk), dim3(NTHR), args, 0, stream);
}

// Round 4
// 277.934 us; speedup vs baseline: 2.5297x; 2.5297x over previous
//
#include <hip/hip_runtime.h>
#include <hip/hip_cooperative_groups.h>

namespace cg = cooperative_groups;

// ConvNet_STDP — single cooperative kernel, speculative fast path + exact repair.
//
// Verified (rounds 1-3, absmax 0.0 each):
//  * STDP provably inert -> weight outputs are clip(w_init, 0, 1).
//  * Network dies at t=0 for this input (alive2==0 after step 0) -> v1/m1/
//    v2/m2/v3/m3 are never read -> fast path skips ALL state writes and fuses
//    conv1+pool1 (z2 never materialized). Exact repair path recomputes t=0
//    state from x0/z3/z5 if speculation fails (general for any input).
//  * Round-3 lesson: __launch_bounds__(,8) forced 32 VGPR -> scratch spills
//    (+68MB writes). Use (256,4): 128-VGPR cap, no spills.

#define T_STEPS 30
#define BATCH   32
#define H_IN    240
#define W_IN    160
#define C1      4
#define H1      236
#define W1O     156
#define H3      39
#define W3      25
#define C2      20
#define H2      24
#define W2O     10
#define C3      10
#define H8      8

#define N_V1   (BATCH*C1*H1*W1O)   // 4,712,448
#define N_V2   (BATCH*C2*H2*W2O)   // 153,600
#define N_V2PB (C2*H2*W2O)         // 4,800
#define N_V3   (BATCH*C3*H8)       // 2,560
#define N_Z3   (BATCH*C1*H3*W3)    // 124,800
#define Z3PB   (C1*H3*W3)          // 3,900
#define N_POOL (BATCH*H3*W3)       // 31,200
#define N_FEAT (BATCH*C3)          // 320

#define NTHR 256

__device__ __forceinline__ void head_block0(
    const unsigned char* __restrict__ z8,
    const float* __restrict__ fc1_w, const float* __restrict__ fc1_b,
    const float* __restrict__ out_w, const float* __restrict__ out_b,
    float* s_feat, float* s_h, float* s_li, float* s_lv,
    float* volts_t, int tid)
{
  for (int i = tid; i < N_FEAT; i += NTHR) {         // z9: OR over 8 spatial
    const unsigned char* p = z8 + i*H8;
    unsigned char r = 0;
    #pragma unroll
    for (int k = 0; k < H8; ++k) r |= p[k];
    s_feat[i] = (float)r;
  }
  __syncthreads();
  {
    int o = tid >> 2, q = tid & 3;                   // 4 lanes per fc1 output
    if (o < 50) {
      const float* wr = fc1_w + (size_t)o*N_FEAT + q*80;
      const float* fr = s_feat + q*80;
      float s = 0.f;
      for (int j = 0; j < 80; ++j) s = fmaf(fr[j], wr[j], s);
      s += __shfl_xor(s, 1, 64);
      s += __shfl_xor(s, 2, 64);
      if (q == 0) s_h[o] = fmaxf(s + fc1_b[o], 0.f);
    }
  }
  __syncthreads();
  if (tid < 10) {
    float idec = s_li[tid]*0.8f;                     // 1 - dt*tau_syn_inv
    float vnew = s_lv[tid] + 0.1f*(idec - s_lv[tid]);
    float acc = idec + out_b[tid];
    for (int k = 0; k < 50; ++k) acc = fmaf(s_h[k], out_w[tid*50 + k], acc);
    s_li[tid] = acc;
    s_lv[tid] = vnew;
  }
  __syncthreads();
  for (int i = tid; i < N_FEAT; i += NTHR) volts_t[i] = s_lv[i % 10];
}

__device__ __forceinline__ void tail_block0(
    int t0, const float* __restrict__ fc1_b,
    const float* __restrict__ out_w, const float* __restrict__ out_b,
    float* s_h, float* s_li, float* s_lv, float* s_tail,
    float* out, int tid)
{
  if (tid < 50) s_h[tid] = fmaxf(fc1_b[tid], 0.f);   // feat==0 -> h=relu(b)
  __syncthreads();
  if (tid < 10) {
    float c = out_b[tid];
    for (int k = 0; k < 50; ++k) c = fmaf(s_h[k], out_w[tid*50 + k], c);
    float li = s_li[tid], lv = s_lv[tid];
    for (int tt = t0; tt < T_STEPS; ++tt) {
      float idec = li*0.8f;
      lv = lv + 0.1f*(idec - lv);
      li = idec + c;
      s_tail[(tt - t0)*10 + tid] = lv;
    }
  }
  __syncthreads();
  int nrem = (T_STEPS - t0)*N_FEAT;
  float* vt = out + (size_t)t0*N_FEAT;
  for (int i = tid; i < nrem; i += NTHR)
    vt[i] = s_tail[(i/N_FEAT)*10 + (i % 10)];
}

__global__ __launch_bounds__(NTHR, 4) void snn_all(
    const float* __restrict__ x,     const float* __restrict__ w1,
    const float* __restrict__ w2,    const float* __restrict__ w3,
    const float* __restrict__ fc1_w, const float* __restrict__ fc1_b,
    const float* __restrict__ out_w, const float* __restrict__ out_b,
    float* __restrict__ out,
    float* v1, float* v2, float* v3,
    unsigned char* m1, unsigned char* m2, unsigned char* m3,
    unsigned char* z2, unsigned char* z3, unsigned char* z5,
    unsigned char* z8, int* alive2)
{
  cg::grid_group grid = cg::this_grid();
  const int tid = threadIdx.x;
  const int gid = blockIdx.x*NTHR + tid;
  const int gsz = gridDim.x*NTHR;

  __shared__ float s_w1[C1*25];
  __shared__ unsigned int s_z3w[(Z3PB+3)/4];
  __shared__ float s_feat[N_FEAT];
  __shared__ float s_h[64];
  __shared__ float s_li[10], s_lv[10];
  __shared__ float s_tail[T_STEPS*10];
  __shared__ int   s_alive;

  float* out_w1 = out + T_STEPS*N_FEAT;
  float* out_w2 = out_w1 + C1*25;

  if (gid == 0) *alive2 = N_V2;
  if (blockIdx.x == 0 && tid < 10) { s_li[tid] = 0.f; s_lv[tid] = 0.f; }
  for (int i = tid; i < C1*25; i += NTHR) s_w1[i] = w1[i];
  __syncthreads();

  // ================= FAST PATH: step t=0, no state writes =================
  // S1: fused conv1+pool1 -> z3. 4 lanes per (b,py,px), window-row split.
  for (int it = gid; it < N_POOL*4; it += gsz) {
    int o = it >> 2, q = it & 3;
    int px = o % W3; int tt = o / W3;
    int py = tt % H3; int b = tt / H3;
    const float* xb = x + (size_t)b*H_IN*W_IN;
    int wy0 = q*2, wy1 = (q < 3) ? q*2 + 2 : 7;
    unsigned mask = 0;
    for (int wy = wy0; wy < wy1; ++wy) {
      int ybase = py*6 + wy;
      for (int wx = 0; wx < 7; ++wx) {
        const float* xw = xb + (size_t)ybase*W_IN + px*6 + wx;
        float s0 = 0.f, s1 = 0.f, s2 = 0.f, s3 = 0.f;
        #pragma unroll
        for (int i = 0; i < 5; ++i) {
          const float* xp = xw + i*W_IN;
          #pragma unroll
          for (int j = 0; j < 5; ++j) {
            float xv = xp[j];
            s0 = fmaf(xv, s_w1[ 0 + i*5 + j], s0);
            s1 = fmaf(xv, s_w1[25 + i*5 + j], s1);
            s2 = fmaf(xv, s_w1[50 + i*5 + j], s2);
            s3 = fmaf(xv, s_w1[75 + i*5 + j], s3);
          }
        }
        mask |= (s0 >= 10.f) ? 1u : 0u;
        mask |= (s1 >= 10.f) ? 2u : 0u;
        mask |= (s2 >= 10.f) ? 4u : 0u;
        mask |= (s3 >= 10.f) ? 8u : 0u;
      }
    }
    mask |= __shfl_xor(mask, 1, 64);
    mask |= __shfl_xor(mask, 2, 64);
    if (q == 0) {
      unsigned char* zp = z3 + (size_t)b*Z3PB + py*W3 + px;
      zp[0]        =  mask       & 1;
      zp[H3*W3]    = (mask >> 1) & 1;
      zp[2*H3*W3]  = (mask >> 2) & 1;
      zp[3*H3*W3]  = (mask >> 3) & 1;
    }
  }
  grid.sync();

  // S2: conv2 + IAF(60) -> z5, alive2. Per-batch LDS staging, 4-lane ci split.
  {
    const int b   = blockIdx.x & 31;
    const int wb  = blockIdx.x >> 5;
    const int bpb = gridDim.x >> 5;
    const unsigned int* zsrc = (const unsigned int*)(z3 + (size_t)b*Z3PB);
    for (int i = tid; i < Z3PB/4; i += NTHR) s_z3w[i] = zsrc[i];
    __syncthreads();
    const unsigned char* sz = (const unsigned char*)s_z3w;
    int nf = 0;
    for (int it = wb*NTHR + tid; it < N_V2PB*4; it += bpb*NTHR) {
      int o = it >> 2, ci = it & 3;
      int c  = o / (H2*W2O);
      int r  = o - c*(H2*W2O);
      int oy = r / W2O, ox = r - (r/W2O)*W2O;
      const float* wp2 = w2 + ((size_t)c*C1 + ci)*256;
      const unsigned char* zb = sz + (ci*H3 + oy)*W3 + ox;
      float s = 0.f;
      #pragma unroll
      for (int i = 0; i < 16; ++i) {
        const unsigned char* ip = zb + i*W3;
        const float* wp = wp2 + i*16;
        #pragma unroll
        for (int j = 0; j < 16; ++j) s = fmaf((float)ip[j], wp[j], s);
      }
      s += __shfl_xor(s, 1, 64);
      s += __shfl_xor(s, 2, 64);
      if (ci == 0) {
        unsigned char sp = (s >= 60.0f) ? 1 : 0;     // t=0: v=s, m=1
        z5[b*N_V2PB + o] = sp;
        nf += sp;
      }
    }
    #pragma unroll
    for (int o2 = 1; o2 < 64; o2 <<= 1) nf += __shfl_xor(nf, o2, 64);
    if ((tid & 63) == 0 && nf) atomicSub(alive2, nf);
  }
  grid.sync();

  // S3: conv3 (pool2 folded) + IAF(2) -> z8. One block per batch.
  if (blockIdx.x < BATCH) {
    const int b = blockIdx.x;
    for (int it = tid; it < C3*H8*4; it += NTHR) {
      int o = it >> 2, g = it & 3;
      int c3 = o >> 3, oy = o & 7;
      float s = 0.f;
      for (int ci = g*5; ci < g*5 + 5; ++ci) {
        const unsigned char* zp = z5 + (size_t)(b*C2 + ci)*H2*W2O;
        const float* wp = w3 + ((size_t)c3*C2 + ci)*25;
        #pragma unroll
        for (int i = 0; i < 5; ++i) {
          const unsigned char* r0 = zp + (2*(oy + i))*W2O;
          const unsigned char* r1 = r0 + W2O;
          #pragma unroll
          for (int j = 0; j < 5; ++j) {
            unsigned char zv = r0[2*j] | r0[2*j+1] | r1[2*j] | r1[2*j+1];
            s = fmaf((float)zv, wp[i*5 + j], s);
          }
        }
      }
      s += __shfl_xor(s, 1, 64);
      s += __shfl_xor(s, 2, 64);
      if (g == 0) z8[b*(C3*H8) + o] = (s >= 2.0f) ? 1 : 0;   // t=0: v=s, m=1
    }
  }
  grid.sync();

  if (tid == 0)
    s_alive = __hip_atomic_load(alive2, __ATOMIC_RELAXED, __HIP_MEMORY_SCOPE_AGENT);
  __syncthreads();
  const int alive0 = s_alive;

  if (blockIdx.x == 0)
    head_block0(z8, fc1_w, fc1_b, out_w, out_b, s_feat, s_h, s_li, s_lv, out, tid);

  if (alive0 == 0) {
    // ---- death confirmed at t=0 (the measured case): closed-form tail, done.
    if (blockIdx.x == 0)
      tail_block0(1, fc1_b, out_w, out_b, s_h, s_li, s_lv, s_tail, out, tid);
    for (int i = gid; i < C1*25;     i += gsz) out_w1[i] = fminf(fmaxf(w1[i], 0.f), 1.f);
    for (int i = gid; i < C2*C1*256; i += gsz) out_w2[i] = fminf(fmaxf(w2[i], 0.f), 1.f);
    return;
  }

  // ============ REPAIR (speculation failed; exact, rarely taken) ============
  // Recompute and store the t=0 states the fast path skipped. x0/z3/z5 intact.
  for (int idx = gid; idx < N_V1; idx += gsz) {
    int xw = idx % W1O; int tt = idx / W1O;
    int y  = tt % H1;   tt /= H1;
    int c  = tt % C1;   int b = tt / C1;
    const float* xp = x + (size_t)(b*H_IN + y)*W_IN + xw;
    const float* wp = s_w1 + c*25;
    float s = 0.f;
    #pragma unroll
    for (int i = 0; i < 5; ++i)
      #pragma unroll
      for (int j = 0; j < 5; ++j) s = fmaf(xp[i*W_IN + j], wp[i*5 + j], s);
    bool z = (s >= 10.0f);
    v1[idx] = z ? 0.f : s;
    m1[idx] = z ? 0 : 1;
  }
  for (int idx = gid; idx < N_V2; idx += gsz) {
    int ox = idx % W2O; int tt = idx / W2O;
    int oy = tt % H2;   tt /= H2;
    int c  = tt % C2;   int b = tt / C2;
    const unsigned char* zb = z3 + (size_t)b*Z3PB;
    const float* wb = w2 + (size_t)c*C1*256;
    float s = 0.f;
    for (int ci = 0; ci < C1; ++ci)
      for (int i = 0; i < 16; ++i) {
        const unsigned char* ip = zb + (ci*H3 + oy + i)*W3 + ox;
        const float* wp = wb + ci*256 + i*16;
        #pragma unroll
        for (int j = 0; j < 16; ++j) s = fmaf((float)ip[j], wp[j], s);
      }
    bool z = (s >= 60.0f);
    v2[idx] = z ? 0.f : s;
    m2[idx] = z ? 0 : 1;
  }
  for (int idx = gid; idx < N_V3; idx += gsz) {
    int oy = idx % H8; int tt = idx / H8;
    int c3 = tt % C3;  int b  = tt / C3;
    float s = 0.f;
    for (int ci = 0; ci < C2; ++ci) {
      const unsigned char* zp = z5 + (size_t)(b*C2 + ci)*H2*W2O;
      const float* wp = w3 + ((size_t)c3*C2 + ci)*25;
      #pragma unroll
      for (int i = 0; i < 5; ++i) {
        const unsigned char* r0 = zp + (2*(oy + i))*W2O;
        const unsigned char* r1 = r0 + W2O;
        #pragma unroll
        for (int j = 0; j < 5; ++j) {
          unsigned char zv = r0[2*j] | r0[2*j+1] | r1[2*j] | r1[2*j+1];
          s = fmaf((float)zv, wp[i*5 + j], s);
        }
      }
    }
    bool z = (s >= 2.0f);
    v3[idx] = z ? 0.f : s;
    m3[idx] = z ? 0 : 1;
  }
  grid.sync();

  // ---- general loop for t >= 1 (round-2/3 verified structure)
  int t = 1;
  for (; t < T_STEPS; ++t) {
    if (t > 1) {
      if (tid == 0)
        s_alive = __hip_atomic_load(alive2, __ATOMIC_RELAXED, __HIP_MEMORY_SCOPE_AGENT);
      __syncthreads();
      if (s_alive == 0) break;
      __syncthreads();
    }
    const float* xt = x + (size_t)t*BATCH*H_IN*W_IN;

    for (int idx = gid; idx < N_V1; idx += gsz) {          // S1: conv1+IAF
      int xw = idx % W1O; int tt = idx / W1O;
      int y  = tt % H1;   tt /= H1;
      int c  = tt % C1;   int b = tt / C1;
      const float* xp = xt + (size_t)(b*H_IN + y)*W_IN + xw;
      const float* wp = s_w1 + c*25;
      float s = 0.f;
      #pragma unroll
      for (int i = 0; i < 5; ++i)
        #pragma unroll
        for (int j = 0; j < 5; ++j) s = fmaf(xp[i*W_IN + j], wp[i*5 + j], s);
      float v = v1[idx] + s;
      bool  z = (v >= 10.0f);
      v1[idx] = z ? 0.f : v;
      unsigned char m = m1[idx];
      z2[idx] = (z && m) ? 1 : 0;
      m1[idx] = (m && !z) ? 1 : 0;
    }
    grid.sync();

    for (int idx = gid; idx < N_Z3; idx += gsz) {          // S2: pool1 = OR
      int px = idx % W3; int tt = idx / W3;
      int py = tt % H3;  tt /= H3;
      int c  = tt % C1;  int b = tt / C1;
      const unsigned char* p = z2 + ((size_t)(b*C1 + c)*H1 + py*6)*W1O + px*6;
      unsigned char r = 0;
      #pragma unroll
      for (int i = 0; i < 7; ++i)
        #pragma unroll
        for (int j = 0; j < 7; ++j) r |= p[i*W1O + j];
      z3[idx] = r;
    }
    grid.sync();

    {                                                      // S3: conv2+IAF
      const int b   = blockIdx.x & 31;
      const int wb  = blockIdx.x >> 5;
      const int bpb = gridDim.x >> 5;
      const unsigned int* zsrc = (const unsigned int*)(z3 + (size_t)b*Z3PB);
      for (int i = tid; i < Z3PB/4; i += NTHR) s_z3w[i] = zsrc[i];
      __syncthreads();
      const unsigned char* sz = (const unsigned char*)s_z3w;
      int nf = 0;
      for (int it = wb*NTHR + tid; it < N_V2PB*4; it += bpb*NTHR) {
        int o = it >> 2, ci = it & 3;
        int c  = o / (H2*W2O);
        int r  = o - c*(H2*W2O);
        int oy = r / W2O, ox = r - (r/W2O)*W2O;
        const float* wp2 = w2 + ((size_t)c*C1 + ci)*256;
        const unsigned char* zb = sz + (ci*H3 + oy)*W3 + ox;
        float s = 0.f;
        #pragma unroll
        for (int i = 0; i < 16; ++i) {
          const unsigned char* ip = zb + i*W3;
          const float* wp = wp2 + i*16;
          #pragma unroll
          for (int j = 0; j < 16; ++j) s = fmaf((float)ip[j], wp[j], s);
        }
        s += __shfl_xor(s, 1, 64);
        s += __shfl_xor(s, 2, 64);
        if (ci == 0) {
          int gidx = b*N_V2PB + o;
          float v = v2[gidx] + s;
          bool  z = (v >= 60.0f);
          v2[gidx] = z ? 0.f : v;
          unsigned char m  = m2[gidx];
          unsigned char sp = (z && m) ? 1 : 0;
          z5[gidx] = sp;
          m2[gidx] = (m && !z) ? 1 : 0;
          nf += sp;
        }
      }
      #pragma unroll
      for (int o2 = 1; o2 < 64; o2 <<= 1) nf += __shfl_xor(nf, o2, 64);
      if ((tid & 63) == 0 && nf) atomicSub(alive2, nf);
    }
    grid.sync();

    if (blockIdx.x < BATCH) {                              // S4: conv3+IAF
      const int b = blockIdx.x;
      for (int it = tid; it < C3*H8*4; it += NTHR) {
        int o = it >> 2, g = it & 3;
        int c3 = o >> 3, oy = o & 7;
        float s = 0.f;
        for (int ci = g*5; ci < g*5 + 5; ++ci) {
          const unsigned char* zp = z5 + (size_t)(b*C2 + ci)*H2*W2O;
          const float* wp = w3 + ((size_t)c3*C2 + ci)*25;
          #pragma unroll
          for (int i = 0; i < 5; ++i) {
            const unsigned char* r0 = zp + (2*(oy + i))*W2O;
            const unsigned char* r1 = r0 + W2O;
            #pragma unroll
            for (int j = 0; j < 5; ++j) {
              unsigned char zv = r0[2*j] | r0[2*j+1] | r1[2*j] | r1[2*j+1];
              s = fmaf((float)zv, wp[i*5 + j], s);
            }
          }
        }
        s += __shfl_xor(s, 1, 64);
        s += __shfl_xor(s, 2, 64);
        if (g == 0) {
          int gidx = b*(C3*H8) + o;
          float v = v3[gidx] + s;
          bool  z = (v >= 2.0f);
          v3[gidx] = z ? 0.f : v;
          unsigned char m = m3[gidx];
          z8[gidx] = (z && m) ? 1 : 0;
          m3[gidx] = (m && !z) ? 1 : 0;
        }
      }
    }
    grid.sync();

    if (blockIdx.x == 0)                                   // S5: head
      head_block0(z8, fc1_w, fc1_b, out_w, out_b, s_feat, s_h, s_li, s_lv,
                  out + (size_t)t*N_FEAT, tid);
    grid.sync();
  }

  if (t < T_STEPS && blockIdx.x == 0)
    tail_block0(t, fc1_b, out_w, out_b, s_h, s_li, s_lv, s_tail, out, tid);
  for (int i = gid; i < C1*25;     i += gsz) out_w1[i] = fminf(fmaxf(w1[i], 0.f), 1.f);
  for (int i = gid; i < C2*C1*256; i += gsz) out_w2[i] = fminf(fmaxf(w2[i], 0.f), 1.f);
}

extern "C" void kernel_launch(void* const* d_in, const int* in_sizes, int n_in,
                              void* d_out, int out_size, void* d_ws, size_t ws_size,
                              hipStream_t stream) {
  const float* x      = (const float*)d_in[0];
  const float* w1     = (const float*)d_in[1];
  const float* w2     = (const float*)d_in[2];
  const float* w3     = (const float*)d_in[3];
  const float* fc1_w  = (const float*)d_in[4];
  const float* fc1_b  = (const float*)d_in[5];
  const float* out_w  = (const float*)d_in[6];
  const float* out_b  = (const float*)d_in[7];
  float* out = (float*)d_out;   // [volts 30*320 | w1 100 | w2 20480]

  char* p = (char*)d_ws;
  float* v1 = (float*)p;            p += (size_t)N_V1*4;
  float* v2 = (float*)p;            p += (size_t)N_V2*4;
  float* v3 = (float*)p;            p += (size_t)N_V3*4;
  int* alive2 = (int*)p;            p += 4;
  unsigned char* m1 = (unsigned char*)p;  p += N_V1;
  unsigned char* m2 = (unsigned char*)p;  p += N_V2;
  unsigned char* m3 = (unsigned char*)p;  p += N_V3;
  unsigned char* z2 = (unsigned char*)p;  p += N_V1;
  unsigned char* z3 = (unsigned char*)p;  p += N_Z3;
  unsigned char* z5 = (unsigned char*)p;  p += N_V2;
  unsigned char* z8 = (unsigned char*)p;  p += N_V3;

  int bpc = 0, cus = 256;
  if (hipOccupancyMaxActiveBlocksPerMultiprocessor(&bpc, snn_all, NTHR, 0) != hipSuccess || bpc < 1)
    bpc = 1;
  (void)hipDeviceGetAttribute(&cus, hipDeviceAttributeMultiprocessorCount, 0);
  int nblk = bpc * cus;
  if (nblk > 1024) nblk = 1024;
  nblk -= nblk % 32;                // batch mappings need a multiple of 32
  if (nblk < 32) nblk = 32;

  void* args[] = {
    (void*)&x, (void*)&w1, (void*)&w2, (void*)&w3,
    (void*)&fc1_w, (void*)&fc1_b, (void*)&out_w, (void*)&out_b,
    (void*)&out,
    (void*)&v1, (void*)&v2, (void*)&v3,
    (void*)&m1, (void*)&m2, (void*)&m3,
    (void*)&z2, (void*)&z3, (void*)&z5, (void*)&z8,
    (void*)&alive2
  };
  hipLaunchCooperativeKernel(reinterpret_cast<void*>(snn_all),
                             dim3(nblk), dim3(NTHR), args, 0, stream);
}

// Round 6
// 126.361 us; speedup vs baseline: 5.5641x; 2.1995x over previous
//
#include <hip/hip_runtime.h>

// ConvNet_STDP — 5 regular kernels, stream-ordered, NO cooperative launch.
//
// Verified (rounds 1-4, absmax 0.0 each):
//  * STDP provably inert -> weight outputs are clip(w_init, 0, 1).
//  * Network dies at t=0 for this input (all m2 cleared) -> z5=z6=z9=0 for
//    t>=1 -> head follows closed-form LI decay.
//  * Batch independence: conv/spike recurrence has NO cross-batch coupling
//    (head only reads z9 and never feeds back) -> no grid-wide syncs needed;
//    the fallback (alive inputs) runs per-batch in one block.
//  * R4 lesson: cooperative dispatch + grid.sync dominated (278us with ~13us
//    of VALU work). Regular launches only (~1-2us each).
//  * R5 bug: k3 used `if (tid < 320)` with 256 threads -> work items 256-319
//    (conv3 channels 8-9) never computed, uninitialized LDS -> absmax 26.5.
//    Fixed: restored the grid-stride loop (R4's verified form).

#define T_STEPS 30
#define BATCH   32
#define H_IN    240
#define W_IN    160
#define C1      4
#define H1      236
#define W1O     156
#define H3      39
#define W3      25
#define C2      20
#define H2      24
#define W2O     10
#define C3      10
#define H8      8

#define N1PB   (C1*H1*W1O)         // 147,264 per-batch conv1 positions
#define N_V1   (BATCH*N1PB)        // 4,712,448
#define N_V2PB (C2*H2*W2O)         // 4,800
#define N_V2   (BATCH*N_V2PB)      // 153,600
#define Z3PB   (C1*H3*W3)          // 3,900
#define N_Z3   (BATCH*Z3PB)        // 124,800
#define N_POOL (BATCH*H3*W3)       // 31,200
#define N_FEAT (BATCH*C3)          // 320

#define NTHR 256

// ---- K1: fused conv1+pool1 (t=0, stateless) -> z3; init alive2 ----
__global__ __launch_bounds__(NTHR) void k1_conv1pool(
    const float* __restrict__ x, const float* __restrict__ w1,
    unsigned char* __restrict__ z3, int* alive2)
{
  __shared__ float s_w1[C1*25];
  for (int i = threadIdx.x; i < C1*25; i += NTHR) s_w1[i] = w1[i];
  __syncthreads();
  int it = blockIdx.x*NTHR + threadIdx.x;
  if (it == 0) *alive2 = N_V2;
  if (it >= N_POOL*4) return;
  int o = it >> 2, q = it & 3;                  // 4 lanes per pooled cell
  int px = o % W3; int tt = o / W3;
  int py = tt % H3; int b = tt / H3;
  const float* xb = x + (size_t)b*H_IN*W_IN;
  int wy0 = q*2, wy1 = (q < 3) ? q*2 + 2 : 7;   // rows 2/2/2/1 of 7x7 window
  unsigned mask = 0;
  for (int wy = wy0; wy < wy1; ++wy) {
    int ybase = py*6 + wy;
    for (int wx = 0; wx < 7; ++wx) {
      const float* xw = xb + (size_t)ybase*W_IN + px*6 + wx;
      float s0 = 0.f, s1 = 0.f, s2 = 0.f, s3 = 0.f;
      #pragma unroll
      for (int i = 0; i < 5; ++i) {
        const float* xp = xw + i*W_IN;
        #pragma unroll
        for (int j = 0; j < 5; ++j) {
          float xv = xp[j];
          s0 = fmaf(xv, s_w1[ 0 + i*5 + j], s0);
          s1 = fmaf(xv, s_w1[25 + i*5 + j], s1);
          s2 = fmaf(xv, s_w1[50 + i*5 + j], s2);
          s3 = fmaf(xv, s_w1[75 + i*5 + j], s3);
        }
      }
      mask |= (s0 >= 10.f) ? 1u : 0u;
      mask |= (s1 >= 10.f) ? 2u : 0u;
      mask |= (s2 >= 10.f) ? 4u : 0u;
      mask |= (s3 >= 10.f) ? 8u : 0u;
    }
  }
  mask |= __shfl_xor(mask, 1, 64);
  mask |= __shfl_xor(mask, 2, 64);
  if (q == 0) {
    unsigned char* zp = z3 + (size_t)b*Z3PB + py*W3 + px;
    zp[0]        =  mask       & 1;
    zp[H3*W3]    = (mask >> 1) & 1;
    zp[2*H3*W3]  = (mask >> 2) & 1;
    zp[3*H3*W3]  = (mask >> 3) & 1;
  }
}

// ---- K2: conv2 + IAF(60) (t=0: v=s, m=1) -> z5; alive2 -= fired ----
__global__ __launch_bounds__(NTHR) void k2_conv2(
    const unsigned char* __restrict__ z3, const float* __restrict__ w2,
    unsigned char* __restrict__ z5, int* alive2)
{
  __shared__ unsigned int s_z3w[Z3PB/4];
  const int b   = blockIdx.x & 31;              // grid is a multiple of 32
  const int wb  = blockIdx.x >> 5;
  const int bpb = gridDim.x >> 5;
  const unsigned int* zsrc = (const unsigned int*)(z3 + (size_t)b*Z3PB);
  for (int i = threadIdx.x; i < Z3PB/4; i += NTHR) s_z3w[i] = zsrc[i];
  __syncthreads();
  const unsigned char* sz = (const unsigned char*)s_z3w;
  int tid = threadIdx.x;
  int nf = 0;
  for (int it = wb*NTHR + tid; it < N_V2PB*4; it += bpb*NTHR) {
    int o = it >> 2, ci = it & 3;               // 4 lanes per output
    int c  = o / (H2*W2O);
    int r  = o - c*(H2*W2O);
    int oy = r / W2O, ox = r - (r/W2O)*W2O;
    const float* wp2 = w2 + ((size_t)c*C1 + ci)*256;
    const unsigned char* zb = sz + (ci*H3 + oy)*W3 + ox;
    float s = 0.f;
    #pragma unroll
    for (int i = 0; i < 16; ++i) {
      const unsigned char* ip = zb + i*W3;
      const float* wp = wp2 + i*16;
      #pragma unroll
      for (int j = 0; j < 16; ++j) s = fmaf((float)ip[j], wp[j], s);
    }
    s += __shfl_xor(s, 1, 64);
    s += __shfl_xor(s, 2, 64);
    if (ci == 0) {
      unsigned char sp = (s >= 60.0f) ? 1 : 0;
      z5[b*N_V2PB + o] = sp;
      nf += sp;
    }
  }
  #pragma unroll
  for (int o2 = 1; o2 < 64; o2 <<= 1) nf += __shfl_xor(nf, o2, 64);
  if ((tid & 63) == 0 && nf) atomicSub(alive2, nf);
}

// ---- K3: conv3 (pool2 folded) + IAF(2) (t=0) -> z9[0]. One block/batch ----
__global__ __launch_bounds__(NTHR) void k3_conv3(
    const unsigned char* __restrict__ z5, const float* __restrict__ w3,
    float* __restrict__ z9)
{
  const int b = blockIdx.x, tid = threadIdx.x;
  __shared__ unsigned int s_z5w[N_V2PB/4];
  __shared__ unsigned char s_z8[C3*H8];
  const unsigned int* zsrc = (const unsigned int*)(z5 + (size_t)b*N_V2PB);
  for (int i = tid; i < N_V2PB/4; i += NTHR) s_z5w[i] = zsrc[i];
  __syncthreads();
  const unsigned char* sz = (const unsigned char*)s_z5w;
  for (int it = tid; it < C3*H8*4; it += NTHR) {   // R5 bug fixed: loop, not if
    int o = it >> 2, g = it & 3;                   // 5-channel group per lane
    int c3 = o >> 3, oy = o & 7;
    float s = 0.f;
    for (int ci = g*5; ci < g*5 + 5; ++ci) {
      const unsigned char* zp = sz + ci*H2*W2O;
      const float* wp = w3 + ((size_t)c3*C2 + ci)*25;
      #pragma unroll
      for (int i = 0; i < 5; ++i) {
        const unsigned char* r0 = zp + (2*(oy + i))*W2O;
        const unsigned char* r1 = r0 + W2O;
        #pragma unroll
        for (int j = 0; j < 5; ++j) {
          unsigned char zv = r0[2*j] | r0[2*j+1] | r1[2*j] | r1[2*j+1];
          s = fmaf((float)zv, wp[i*5 + j], s);
        }
      }
    }
    s += __shfl_xor(s, 1, 64);
    s += __shfl_xor(s, 2, 64);
    if (g == 0) s_z8[o] = (s >= 2.0f) ? 1 : 0;
  }
  __syncthreads();
  if (tid < C3) {
    unsigned char r = 0;
    #pragma unroll
    for (int k = 0; k < H8; ++k) r |= s_z8[tid*H8 + k];
    z9[b*C3 + tid] = (float)r;                  // z9[t=0][b][c]
  }
}

// ---- F1: gated exact fallback — per-batch repair of t=0 state + full
//      t=1..29 recurrence. Returns immediately when alive2==0 (measured). ----
__global__ __launch_bounds__(NTHR) void f1_fallback(
    const float* __restrict__ x,  const float* __restrict__ w1,
    const float* __restrict__ w2, const float* __restrict__ w3,
    const unsigned char* __restrict__ z3g, const unsigned char* __restrict__ z5g,
    float* v1, unsigned char* m1, unsigned char* z2,
    float* __restrict__ z9, const int* alive2)
{
  if (*alive2 == 0) return;
  const int b = blockIdx.x, tid = threadIdx.x;
  __shared__ float s_w1[C1*25];
  __shared__ unsigned char s_z3[Z3PB];
  __shared__ float s_v2[N_V2PB];
  __shared__ unsigned char s_m2[N_V2PB], s_z5[N_V2PB];
  __shared__ float s_v3[C3*H8];
  __shared__ unsigned char s_m3[C3*H8], s_z8[C3*H8];

  for (int i = tid; i < C1*25; i += NTHR) s_w1[i] = w1[i];
  float* v1b = v1 + (size_t)b*N1PB;
  unsigned char* m1b = m1 + (size_t)b*N1PB;
  unsigned char* z2b = z2 + (size_t)b*N1PB;
  __syncthreads();

  // repair t=0: conv1 state
  const float* x0 = x + (size_t)b*H_IN*W_IN;
  for (int idx = tid; idx < N1PB; idx += NTHR) {
    int xw = idx % W1O; int r = idx / W1O;
    int y  = r % H1;    int c = r / H1;
    const float* xp = x0 + (size_t)y*W_IN + xw;
    const float* wp = s_w1 + c*25;
    float s = 0.f;
    #pragma unroll
    for (int i = 0; i < 5; ++i)
      #pragma unroll
      for (int j = 0; j < 5; ++j) s = fmaf(xp[i*W_IN + j], wp[i*5 + j], s);
    bool z = (s >= 10.0f);
    v1b[idx] = z ? 0.f : s;
    m1b[idx] = z ? 0 : 1;
  }
  // repair t=0: conv2 state (from K1's z3)
  for (int i = tid; i < Z3PB; i += NTHR) s_z3[i] = z3g[(size_t)b*Z3PB + i];
  __syncthreads();
  for (int o = tid; o < N_V2PB; o += NTHR) {
    int c  = o / (H2*W2O);
    int r  = o - c*(H2*W2O);
    int oy = r / W2O, ox = r - (r/W2O)*W2O;
    const float* wb = w2 + (size_t)c*C1*256;
    float s = 0.f;
    for (int ci = 0; ci < C1; ++ci)
      for (int i = 0; i < 16; ++i) {
        const unsigned char* ip = s_z3 + (ci*H3 + oy + i)*W3 + ox;
        const float* wp = wb + ci*256 + i*16;
        #pragma unroll
        for (int j = 0; j < 16; ++j) s = fmaf((float)ip[j], wp[j], s);
      }
    bool z = (s >= 60.0f);
    s_v2[o] = z ? 0.f : s;
    s_m2[o] = z ? 0 : 1;
  }
  // repair t=0: conv3 state (from K2's z5)
  for (int i = tid; i < N_V2PB; i += NTHR) s_z5[i] = z5g[(size_t)b*N_V2PB + i];
  __syncthreads();
  for (int o = tid; o < C3*H8; o += NTHR) {
    int c3 = o >> 3, oy = o & 7;
    float s = 0.f;
    for (int ci = 0; ci < C2; ++ci) {
      const unsigned char* zp = s_z5 + ci*H2*W2O;
      const float* wp = w3 + ((size_t)c3*C2 + ci)*25;
      #pragma unroll
      for (int i = 0; i < 5; ++i) {
        const unsigned char* r0 = zp + (2*(oy + i))*W2O;
        const unsigned char* r1 = r0 + W2O;
        #pragma unroll
        for (int j = 0; j < 5; ++j) {
          unsigned char zv = r0[2*j] | r0[2*j+1] | r1[2*j] | r1[2*j+1];
          s = fmaf((float)zv, wp[i*5 + j], s);
        }
      }
    }
    bool z = (s >= 2.0f);
    s_v3[o] = z ? 0.f : s;
    s_m3[o] = z ? 0 : 1;
  }
  __syncthreads();

  // exact recurrence t = 1..29 for this batch
  for (int t = 1; t < T_STEPS; ++t) {
    const float* xt = x + ((size_t)t*BATCH + b)*H_IN*W_IN;
    for (int idx = tid; idx < N1PB; idx += NTHR) {        // conv1+IAF
      int xw = idx % W1O; int r = idx / W1O;
      int y  = r % H1;    int c = r / H1;
      const float* xp = xt + (size_t)y*W_IN + xw;
      const float* wp = s_w1 + c*25;
      float s = 0.f;
      #pragma unroll
      for (int i = 0; i < 5; ++i)
        #pragma unroll
        for (int j = 0; j < 5; ++j) s = fmaf(xp[i*W_IN + j], wp[i*5 + j], s);
      float v = v1b[idx] + s;
      bool  z = (v >= 10.0f);
      v1b[idx] = z ? 0.f : v;
      unsigned char m = m1b[idx];
      z2b[idx] = (z && m) ? 1 : 0;
      m1b[idx] = (m && !z) ? 1 : 0;
    }
    __syncthreads();
    for (int i = tid; i < Z3PB; i += NTHR) {              // pool1 = OR
      int px = i % W3; int r = i / W3;
      int py = r % H3; int c = r / H3;
      const unsigned char* p = z2b + ((size_t)c*H1 + py*6)*W1O + px*6;
      unsigned char rr = 0;
      #pragma unroll
      for (int ii = 0; ii < 7; ++ii)
        #pragma unroll
        for (int jj = 0; jj < 7; ++jj) rr |= p[ii*W1O + jj];
      s_z3[i] = rr;
    }
    __syncthreads();
    for (int o = tid; o < N_V2PB; o += NTHR) {            // conv2+IAF
      int c  = o / (H2*W2O);
      int r  = o - c*(H2*W2O);
      int oy = r / W2O, ox = r - (r/W2O)*W2O;
      const float* wb = w2 + (size_t)c*C1*256;
      float s = 0.f;
      for (int ci = 0; ci < C1; ++ci)
        for (int i = 0; i < 16; ++i) {
          const unsigned char* ip = s_z3 + (ci*H3 + oy + i)*W3 + ox;
          const float* wp = wb + ci*256 + i*16;
          #pragma unroll
          for (int j = 0; j < 16; ++j) s = fmaf((float)ip[j], wp[j], s);
        }
      float v = s_v2[o] + s;
      bool  z = (v >= 60.0f);
      s_v2[o] = z ? 0.f : v;
      unsigned char m = s_m2[o];
      s_z5[o] = (z && m) ? 1 : 0;
      s_m2[o] = (m && !z) ? 1 : 0;
    }
    __syncthreads();
    for (int o = tid; o < C3*H8; o += NTHR) {             // conv3+IAF (pool folded)
      int c3 = o >> 3, oy = o & 7;
      float s = 0.f;
      for (int ci = 0; ci < C2; ++ci) {
        const unsigned char* zp = s_z5 + ci*H2*W2O;
        const float* wp = w3 + ((size_t)c3*C2 + ci)*25;
        #pragma unroll
        for (int i = 0; i < 5; ++i) {
          const unsigned char* r0 = zp + (2*(oy + i))*W2O;
          const unsigned char* r1 = r0 + W2O;
          #pragma unroll
          for (int j = 0; j < 5; ++j) {
            unsigned char zv = r0[2*j] | r0[2*j+1] | r1[2*j] | r1[2*j+1];
            s = fmaf((float)zv, wp[i*5 + j], s);
          }
        }
      }
      float v = s_v3[o] + s;
      bool  z = (v >= 2.0f);
      s_v3[o] = z ? 0.f : v;
      unsigned char m = s_m3[o];
      s_z8[o] = (z && m) ? 1 : 0;
      s_m3[o] = (m && !z) ? 1 : 0;
    }
    __syncthreads();
    if (tid < C3) {                                       // z9[t][b][c]
      unsigned char r = 0;
      #pragma unroll
      for (int k = 0; k < H8; ++k) r |= s_z8[tid*H8 + k];
      z9[(size_t)t*N_FEAT + b*C3 + tid] = (float)r;
    }
    __syncthreads();
  }
}

// ---- F2: readout head for all 30 steps (closed-form tail when dead) +
//      weight-clip outputs ----
__global__ __launch_bounds__(NTHR) void f2_head(
    const float* __restrict__ z9,
    const float* __restrict__ fc1_w, const float* __restrict__ fc1_b,
    const float* __restrict__ out_w, const float* __restrict__ out_b,
    const float* __restrict__ w1,    const float* __restrict__ w2,
    float* __restrict__ out, const int* alive2)
{
  const int tid = threadIdx.x;
  const int gid = blockIdx.x*NTHR + tid;
  const int gsz = gridDim.x*NTHR;
  float* out_w1 = out + T_STEPS*N_FEAT;
  float* out_w2 = out_w1 + C1*25;
  for (int i = gid; i < C1*25;     i += gsz) out_w1[i] = fminf(fmaxf(w1[i], 0.f), 1.f);
  for (int i = gid; i < C2*C1*256; i += gsz) out_w2[i] = fminf(fmaxf(w2[i], 0.f), 1.f);
  if (blockIdx.x != 0) return;

  __shared__ float s_feat[N_FEAT], s_h[64], s_li[10], s_lv[10];
  __shared__ float s_tail[T_STEPS*10];
  if (tid < 10) { s_li[tid] = 0.f; s_lv[tid] = 0.f; }
  __syncthreads();
  const bool alive = (*alive2 != 0);
  const int tmax = alive ? T_STEPS : 1;

  for (int t = 0; t < tmax; ++t) {
    for (int i = tid; i < N_FEAT; i += NTHR) s_feat[i] = z9[(size_t)t*N_FEAT + i];
    __syncthreads();
    {
      int o = tid >> 2, q = tid & 3;            // 4 lanes per fc1 output
      if (o < 50) {
        const float* wr = fc1_w + (size_t)o*N_FEAT + q*80;
        const float* fr = s_feat + q*80;
        float s = 0.f;
        for (int j = 0; j < 80; ++j) s = fmaf(fr[j], wr[j], s);
        s += __shfl_xor(s, 1, 64);
        s += __shfl_xor(s, 2, 64);
        if (q == 0) s_h[o] = fmaxf(s + fc1_b[o], 0.f);
      }
    }
    __syncthreads();
    if (tid < 10) {
      float idec = s_li[tid]*0.8f;              // 1 - dt*tau_syn_inv
      float vnew = s_lv[tid] + 0.1f*(idec - s_lv[tid]);
      float acc = idec + out_b[tid];
      for (int k = 0; k < 50; ++k) acc = fmaf(s_h[k], out_w[tid*50 + k], acc);
      s_li[tid] = acc;
      s_lv[tid] = vnew;
    }
    __syncthreads();
    float* vt = out + (size_t)t*N_FEAT;
    for (int i = tid; i < N_FEAT; i += NTHR) vt[i] = s_lv[i % 10];
    __syncthreads();
  }

  if (!alive) {                                 // closed-form tail t=1..29
    if (tid < 50) s_h[tid] = fmaxf(fc1_b[tid], 0.f);
    __syncthreads();
    if (tid < 10) {
      float c = out_b[tid];
      for (int k = 0; k < 50; ++k) c = fmaf(s_h[k], out_w[tid*50 + k], c);
      float li = s_li[tid], lv = s_lv[tid];
      for (int tt = 1; tt < T_STEPS; ++tt) {
        float idec = li*0.8f;
        lv = lv + 0.1f*(idec - lv);
        li = idec + c;
        s_tail[(tt - 1)*10 + tid] = lv;
      }
    }
    __syncthreads();
    int nrem = (T_STEPS - 1)*N_FEAT;
    float* vt = out + (size_t)N_FEAT;
    for (int i = tid; i < nrem; i += NTHR)
      vt[i] = s_tail[(i/N_FEAT)*10 + (i % 10)];
  }
}

extern "C" void kernel_launch(void* const* d_in, const int* in_sizes, int n_in,
                              void* d_out, int out_size, void* d_ws, size_t ws_size,
                              hipStream_t stream) {
  const float* x      = (const float*)d_in[0];
  const float* w1     = (const float*)d_in[1];
  const float* w2     = (const float*)d_in[2];
  const float* w3     = (const float*)d_in[3];
  const float* fc1_w  = (const float*)d_in[4];
  const float* fc1_b  = (const float*)d_in[5];
  const float* out_w  = (const float*)d_in[6];
  const float* out_b  = (const float*)d_in[7];
  float* out = (float*)d_out;   // [volts 30*320 | w1 100 | w2 20480]

  char* p = (char*)d_ws;
  float* v1 = (float*)p;                  p += (size_t)N_V1*4;
  float* z9 = (float*)p;                  p += (size_t)T_STEPS*N_FEAT*4;
  int* alive2 = (int*)p;                  p += 4;
  p += 60;                                // pad to 64B
  unsigned char* m1 = (unsigned char*)p;  p += N_V1;
  unsigned char* z2 = (unsigned char*)p;  p += N_V1;
  unsigned char* z3 = (unsigned char*)p;  p += N_Z3;
  unsigned char* z5 = (unsigned char*)p;  p += N_V2;

  k1_conv1pool<<<488, NTHR, 0, stream>>>(x, w1, z3, alive2);
  k2_conv2<<<512, NTHR, 0, stream>>>(z3, w2, z5, alive2);
  k3_conv3<<<BATCH, NTHR, 0, stream>>>(z5, w3, z9);
  f1_fallback<<<BATCH, NTHR, 0, stream>>>(x, w1, w2, w3, z3, z5,
                                          v1, m1, z2, z9, alive2);
  f2_head<<<64, NTHR, 0, stream>>>(z9, fc1_w, fc1_b, out_w, out_b,
                                   w1, w2, out, alive2);
}